// Round 2
// baseline (860.565 us; speedup 1.0000x reference)
//
#include <hip/hip_runtime.h>
#include <math.h>

// DeepSetStrategyModel: E edges, C candidates, EMB=32, EDGE_DIM=1.
// Algebraic restructure (EDGE_DIM==1 => everything affine in scalar a_e):
//   U = wv@w_t1, V = bv@w_t1 + b_t1
//   g[c][k] = sum_{e in c} relu(a_e*U[k]+V[k])
//   S[c] = n_c*m0 + g[c]@M,  M = w_t2@w_u1_bot, m0 = b_t2@w_u1_bot
//   z2 = a*P + Q + S[src],  P = wv@w_u1_top, Q = bv@w_u1_top + b_u1
//   out = relu(z2)@w_u2 + b_u2
//
// Piecewise-linear scatter (this round's change): relu(a*U_k+V_k) is linear in
// a on either side of t_k = -V_k/U_k. With the 32 thresholds sorted, an edge
// only needs its bucket b = #{T_i < a} and TWO atomics (sum_a, count) instead
// of 32: g[c][k] = U_k*Sum_active + V_k*Cnt_active where the active set is a
// bucket suffix (U_k>0) or prefix (U_k<0).

#define EMB 32

// wsc layout (floats):
//   [0,32)     U
//   [32,64)    V
//   [64,96)    P
//   [96,128)   Q
//   [128,160)  m0
//   [160,1184) M  (M[i][k] at 160+i*32+k)
//   [1184,1216) T  sorted thresholds
//   [1216,1248) rank r_k (as float)
//   [1248,1280) class: +1 (U>0), -1 (U<0), 0 (U==0)
__global__ void precompute_kernel(const float* __restrict__ w_v2h,
                                  const float* __restrict__ b_v2h,
                                  const float* __restrict__ w_t1,
                                  const float* __restrict__ b_t1,
                                  const float* __restrict__ w_t2,
                                  const float* __restrict__ b_t2,
                                  const float* __restrict__ w_u1,
                                  const float* __restrict__ b_u1,
                                  float* __restrict__ wsc) {
    int t = threadIdx.x;        // 0..1023
    int k = t & 31;
    int i = t >> 5;
    // M[i][k] = sum_j w_t2[i][j] * w_u1[32+j][k]
    float m = 0.f;
#pragma unroll
    for (int j = 0; j < 32; ++j)
        m = fmaf(w_t2[i * 32 + j], w_u1[(32 + j) * 32 + k], m);
    wsc[160 + i * 32 + k] = m;
    if (i == 0) {               // lanes 0..31 of wave 0
        float u = 0.f, v = 0.f, p = 0.f, q = 0.f, m0 = 0.f;
#pragma unroll
        for (int j = 0; j < 32; ++j) {
            float wv = w_v2h[j];
            float bv = b_v2h[j];
            u  = fmaf(wv, w_t1[j * 32 + k], u);
            v  = fmaf(bv, w_t1[j * 32 + k], v);
            p  = fmaf(wv, w_u1[j * 32 + k], p);
            q  = fmaf(bv, w_u1[j * 32 + k], q);
            m0 = fmaf(b_t2[j], w_u1[(32 + j) * 32 + k], m0);
        }
        float U = u;
        float V = v + b_t1[k];
        wsc[0 + k]   = U;
        wsc[32 + k]  = V;
        wsc[64 + k]  = p;
        wsc[96 + k]  = q + b_u1[k];
        wsc[128 + k] = m0;

        // threshold + class
        float tk;
        float cls;
        if (U > 0.f)      { tk = -V / U;   cls = 1.f; }
        else if (U < 0.f) { tk = -V / U;   cls = -1.f; }
        else              { tk = INFINITY; cls = 0.f; }   // const case, excluded
        // stable rank within lanes 0..31 (all in wave 0, lockstep)
        int r = 0;
#pragma unroll
        for (int j = 0; j < 32; ++j) {
            float tj = __shfl(tk, j, 32);
            r += (tj < tk) || (tj == tk && j < k);
        }
        wsc[1184 + r] = tk;        // sorted thresholds
        wsc[1216 + k] = (float)r;  // rank per k
        wsc[1248 + k] = cls;
    }
}

// ---------------- phase 1: 2 atomics per edge into (sum, cnt) bucket --------
// buf[c*68 + 2*b]   += a        (b = # sorted thresholds < a, in [0,32])
// buf[c*68 + 2*b+1] += 1.0f     (float count; E < 2^24 so exact)
__global__ __launch_bounds__(256) void phase1_kernel(
        const float* __restrict__ attr,
        const int* __restrict__ src,
        const float* __restrict__ wsc,
        float* __restrict__ buf,
        int E) {
    int e = blockIdx.x * 256 + threadIdx.x;
    if (e >= E) return;
    float a = attr[e];
    int c = src[e];
    int b = 0;
#pragma unroll
    for (int i = 0; i < 32; ++i)
        b += (wsc[1184 + i] < a) ? 1 : 0;     // T is thread-invariant (s_load)
    float* p = buf + (size_t)c * 68 + 2 * b;
    unsafeAtomicAdd(p, a);
    unsafeAtomicAdd(p + 1, 1.0f);
}

// ---------------- per-candidate: buckets -> g -> S (in place, S at buf[c*68+k])
// 32 lanes per candidate (one half-wave); each candidate's region is read and
// written only by its own lockstep 32-group, so in-place is race-free.
__global__ __launch_bounds__(256) void sscore_kernel(
        float* __restrict__ buf,
        const float* __restrict__ wsc,
        int C) {
    unsigned int gid = blockIdx.x * 256u + threadIdx.x;
    int c = (int)(gid >> 5);
    int k = (int)(gid & 31u);
    if (c >= C) return;
    int   r   = (int)wsc[1216 + k];
    float cls = wsc[1248 + k];
    float U   = wsc[k];
    float V   = wsc[32 + k];
    float* bp = buf + (size_t)c * 68;
    float sumLE = 0.f, cntLE = 0.f, sumT = 0.f, cntT = 0.f;
    for (int b = 0; b <= 32; ++b) {
        float s = bp[2 * b];
        float n = bp[2 * b + 1];
        sumT += s; cntT += n;
        if (b <= r) { sumLE += s; cntLE += n; }
    }
    float g;
    if (cls > 0.f)      g = U * (sumT - sumLE) + V * (cntT - cntLE);  // a > t_k
    else if (cls < 0.f) g = U * sumLE + V * cntLE;                    // a < t_k
    else                g = fmaxf(V, 0.f) * cntT;                     // U == 0
    // S[c][k] = n_c*m0[k] + sum_j g_j * M[j][k]
    float s = cntT * wsc[128 + k];
    const float* M = wsc + 160;
#pragma unroll
    for (int j = 0; j < 32; ++j)
        s = fmaf(__shfl(g, j, 32), M[j * 32 + k], s);
    bp[k] = s;   // all reads of bp[0..65] completed (lockstep wave) before store
}

// ---------------- phase 2: out[e][k] = relu(a*P+Q+S[src])@w_u2 + b_u2 -------
// 32 lanes per edge (lane = output column k). Coalesced S-gather (128B per
// half-wave) and coalesced 256B/wave output stores. w_u2 column preloaded in
// 32 VGPRs, amortized by grid-stride loop.
__global__ __launch_bounds__(256) void phase2_kernel(
        const float* __restrict__ attr,
        const int* __restrict__ src,
        const float* __restrict__ buf,    // S at buf[c*68 + k]
        const float* __restrict__ wsc,
        const float* __restrict__ w_u2,
        const float* __restrict__ b_u2,
        float* __restrict__ out,
        int E) {
    int k = threadIdx.x & 31;
    int grp = (blockIdx.x * 256 + threadIdx.x) >> 5;
    int ngrp = gridDim.x * 8;                 // 256/32 groups per block
    float P = wsc[64 + k];
    float Q = wsc[96 + k];
    float B2 = b_u2[k];
    float w2[32];
#pragma unroll
    for (int j = 0; j < 32; ++j) w2[j] = w_u2[j * 32 + k];

    for (int e = grp; e < E; e += ngrp) {
        float a = attr[e];                    // 32-lane broadcast load
        int c = src[e];
        float S = buf[(size_t)c * 68 + k];    // contiguous 128B per half-wave
        float rr = fmaxf(fmaf(a, P, Q) + S, 0.f);
        float acc = B2;
#pragma unroll
        for (int j = 0; j < 32; ++j)
            acc = fmaf(__shfl(rr, j, 32), w2[j], acc);
        out[(size_t)e * 32 + k] = acc;        // 256B contiguous per wave
    }
}

extern "C" void kernel_launch(void* const* d_in, const int* in_sizes, int n_in,
                              void* d_out, int out_size, void* d_ws, size_t ws_size,
                              hipStream_t stream) {
    const float* attr   = (const float*)d_in[0];
    const int*   eidx   = (const int*)d_in[1];   // src = first E entries
    const float* w_v2h  = (const float*)d_in[3];
    const float* b_v2h  = (const float*)d_in[4];
    const float* w_t1   = (const float*)d_in[5];
    const float* b_t1   = (const float*)d_in[6];
    const float* w_t2   = (const float*)d_in[7];
    const float* b_t2   = (const float*)d_in[8];
    const float* w_u1   = (const float*)d_in[9];
    const float* b_u1   = (const float*)d_in[10];
    const float* w_u2   = (const float*)d_in[11];
    const float* b_u2   = (const float*)d_in[12];
    float* out = (float*)d_out;

    int E = in_sizes[0];          // edge_attr is E x 1
    int C = in_sizes[2];          // candidate_idxs length

    // ws layout: buf (C*68 f32: 33 (sum,cnt) pairs + pad; S reuses [0,32)) | wsc
    float* buf = (float*)d_ws;
    float* wsc = buf + (size_t)C * 68;

    hipMemsetAsync(buf, 0, (size_t)C * 68 * sizeof(float), stream);

    precompute_kernel<<<1, 1024, 0, stream>>>(w_v2h, b_v2h, w_t1, b_t1,
                                              w_t2, b_t2, w_u1, b_u1, wsc);

    phase1_kernel<<<(E + 255) / 256, 256, 0, stream>>>(attr, eidx, wsc, buf, E);

    sscore_kernel<<<((unsigned)C * 32u + 255) / 256, 256, 0, stream>>>(buf, wsc, C);

    phase2_kernel<<<2048, 256, 0, stream>>>(attr, eidx, buf, wsc,
                                            w_u2, b_u2, out, E);
}

// Round 3
// 477.933 us; speedup vs baseline: 1.8006x; 1.8006x over previous
//
#include <hip/hip_runtime.h>
#include <math.h>

// DeepSetStrategyModel: E edges, C candidates, EMB=32, EDGE_DIM=1.
// Algebra (EDGE_DIM==1 => affine in scalar a_e):
//   U = wv@w_t1, V = bv@w_t1 + b_t1
//   g[c][k] = sum_{e in c} relu(a_e*U[k]+V[k])
//   S[c] = n_c*m0 + g[c]@M,  M = w_t2@w_u1_bot, m0 = b_t2@w_u1_bot
//   out[e] = relu(a*P + Q + S[src]) @ w_u2 + b_u2
// Piecewise-linear bucket trick: with sorted thresholds T (t_k = -V_k/U_k),
// per candidate we only need (sum_a, count) per bucket b = #{T_i < a}.
// R3 change: phase1 via per-block LDS bins (no global atomic scatter);
// phase2 via LDS-staged tiles (coalesced gather/store, no shfl).

#define EMB 32

// wsc layout (floats):
//   [0,32) U | [32,64) V | [64,96) P | [96,128) Q | [128,160) m0
//   [160,1184) M (M[i][k] at 160+i*32+k)
//   [1184,1216) T sorted | [1216,1248) rank r_k | [1248,1280) class
__global__ void precompute_kernel(const float* __restrict__ w_v2h,
                                  const float* __restrict__ b_v2h,
                                  const float* __restrict__ w_t1,
                                  const float* __restrict__ b_t1,
                                  const float* __restrict__ w_t2,
                                  const float* __restrict__ b_t2,
                                  const float* __restrict__ w_u1,
                                  const float* __restrict__ b_u1,
                                  float* __restrict__ wsc) {
    int t = threadIdx.x;        // 0..1023
    int k = t & 31;
    int i = t >> 5;
    float m = 0.f;
#pragma unroll
    for (int j = 0; j < 32; ++j)
        m = fmaf(w_t2[i * 32 + j], w_u1[(32 + j) * 32 + k], m);
    wsc[160 + i * 32 + k] = m;
    if (i == 0) {               // lanes 0..31 of wave 0
        float u = 0.f, v = 0.f, p = 0.f, q = 0.f, m0 = 0.f;
#pragma unroll
        for (int j = 0; j < 32; ++j) {
            float wv = w_v2h[j];
            float bv = b_v2h[j];
            u  = fmaf(wv, w_t1[j * 32 + k], u);
            v  = fmaf(bv, w_t1[j * 32 + k], v);
            p  = fmaf(wv, w_u1[j * 32 + k], p);
            q  = fmaf(bv, w_u1[j * 32 + k], q);
            m0 = fmaf(b_t2[j], w_u1[(32 + j) * 32 + k], m0);
        }
        float U = u;
        float V = v + b_t1[k];
        wsc[0 + k]   = U;
        wsc[32 + k]  = V;
        wsc[64 + k]  = p;
        wsc[96 + k]  = q + b_u1[k];
        wsc[128 + k] = m0;
        float tk, cls;
        if (U > 0.f)      { tk = -V / U;   cls = 1.f; }
        else if (U < 0.f) { tk = -V / U;   cls = -1.f; }
        else              { tk = INFINITY; cls = 0.f; }
        int r = 0;
#pragma unroll
        for (int j = 0; j < 32; ++j) {
            float tj = __shfl(tk, j, 32);
            r += (tj < tk) || (tj == tk && j < k);
        }
        wsc[1184 + r] = tk;
        wsc[1216 + k] = (float)r;
        wsc[1248 + k] = cls;
    }
}

// ---- pass0: pack (a, key = bucket<<14 | c) per edge, one float2 write ------
__global__ __launch_bounds__(256) void pass0_kernel(
        const float* __restrict__ attr,
        const int* __restrict__ src,
        const float* __restrict__ wsc,
        float2* __restrict__ pk,
        int E) {
    int e = blockIdx.x * 256 + threadIdx.x;
    if (e >= E) return;
    float a = attr[e];
    int c = src[e];
    int bk = 0;
#pragma unroll
    for (int i = 0; i < 32; ++i)
        bk += (wsc[1184 + i] < a) ? 1 : 0;   // T uniform -> s_loads
    pk[e] = make_float2(a, __int_as_float((bk << 14) | c));
}

// ---- phase 1: LDS-binned bucket accumulation -------------------------------
// Grid = NP1 ranges x CH1 edge-chunks. Block owns LDS tile for R1 candidates
// x 33 (sum,cnt) buckets; scans its chunk, ds_add_f32 for in-range edges;
// merges tile to global buf with contiguous zero-skipped atomics.
#define R1  240
#define NP1 42      // 42*240 = 10080 >= C
#define CH1 6

__global__ __launch_bounds__(1024) void phase1_kernel(
        const float2* __restrict__ pk,
        const float* __restrict__ attr,
        const int* __restrict__ src,
        const float* __restrict__ wsc,
        float* __restrict__ buf,
        int E, int C, int useKey) {
    __shared__ float tile[R1 * 66];           // 63360 B
    int rng = blockIdx.x % NP1;
    int ch  = blockIdx.x / NP1;
    int clo = rng * R1;
    for (int i = threadIdx.x; i < R1 * 66; i += 1024) tile[i] = 0.f;
    __syncthreads();
    int cpe = (E + CH1 - 1) / CH1;
    int es = ch * cpe;
    int ee = min(E, es + cpe);
    if (useKey) {
        for (int e = es + (int)threadIdx.x; e < ee; e += 1024) {
            float2 v = pk[e];
            int key = __float_as_int(v.y);
            unsigned rc = (unsigned)((key & 16383) - clo);
            if (rc < R1) {
                float* p = tile + rc * 66 + 2 * (key >> 14);
                atomicAdd(p, v.x);            // ds_add_f32
                atomicAdd(p + 1, 1.0f);
            }
        }
    } else {
        for (int e = es + (int)threadIdx.x; e < ee; e += 1024) {
            int c = src[e];
            unsigned rc = (unsigned)(c - clo);
            if (rc < R1) {
                float a = attr[e];
                int bk = 0;
#pragma unroll
                for (int i = 0; i < 32; ++i)
                    bk += (wsc[1184 + i] < a) ? 1 : 0;
                float* p = tile + rc * 66 + 2 * bk;
                atomicAdd(p, a);
                atomicAdd(p + 1, 1.0f);
            }
        }
    }
    __syncthreads();
    for (int i = threadIdx.x; i < R1 * 66; i += 1024) {
        float v = tile[i];
        if (v != 0.f) {                       // untouched slots add nothing
            int j = i / 66;
            int w = i - j * 66;
            unsafeAtomicAdd(&buf[(size_t)(clo + j) * 68 + w], v);
        }
    }
}

// ---- per-candidate: buckets -> g -> S into sarr[c*32+k] --------------------
__global__ __launch_bounds__(256) void sscore_kernel(
        const float* __restrict__ buf,
        const float* __restrict__ wsc,
        float* __restrict__ sarr,
        int C) {
    unsigned int gid = blockIdx.x * 256u + threadIdx.x;
    int c = (int)(gid >> 5);
    int k = (int)(gid & 31u);
    if (c >= C) return;
    int   r   = (int)wsc[1216 + k];
    float cls = wsc[1248 + k];
    float U   = wsc[k];
    float V   = wsc[32 + k];
    const float* bp = buf + (size_t)c * 68;
    float sumLE = 0.f, cntLE = 0.f, sumT = 0.f, cntT = 0.f;
    for (int b = 0; b <= 32; ++b) {
        float s = bp[2 * b];
        float n = bp[2 * b + 1];
        sumT += s; cntT += n;
        if (b <= r) { sumLE += s; cntLE += n; }
    }
    float g;
    if (cls > 0.f)      g = U * (sumT - sumLE) + V * (cntT - cntLE);
    else if (cls < 0.f) g = U * sumLE + V * cntLE;
    else                g = fmaxf(V, 0.f) * cntT;
    float s = cntT * wsc[128 + k];
    const float* M = wsc + 160;
#pragma unroll
    for (int j = 0; j < 32; ++j)
        s = fmaf(__shfl(g, j, 32), M[j * 32 + k], s);
    sarr[(size_t)c * 32 + k] = s;
}

// ---- phase 2: LDS-staged tile of 256 edges ---------------------------------
// Cooperative S gather (32 lanes per row -> 2 lines/row), per-thread 32x32
// matvec in registers, LDS transpose (+1 pad) -> coalesced 256B/wave stores.
__global__ __launch_bounds__(256) void phase2_kernel(
        const float* __restrict__ attr,
        const int* __restrict__ src,
        const float* __restrict__ sarr,
        const float* __restrict__ wsc,
        const float* __restrict__ w_u2,
        const float* __restrict__ b_u2,
        float* __restrict__ out,
        int E) {
    __shared__ float sld[256 * 33];           // 33792 B
    __shared__ int   sc[256];
    int tid  = threadIdx.x;
    int e0   = blockIdx.x * 256;
    int n    = min(256, E - e0);
    int lane = tid & 31;
    int grp  = tid >> 5;

    if (tid < n) sc[tid] = src[e0 + tid];
    __syncthreads();
    for (int i = grp; i < n; i += 8)
        sld[i * 33 + lane] = sarr[(size_t)sc[i] * 32 + lane];
    __syncthreads();

    if (tid < n) {
        float a = attr[e0 + tid];
        float z[32];
#pragma unroll
        for (int k = 0; k < 32; ++k) {
            float S = sld[tid * 33 + k];
            z[k] = fmaxf(fmaf(a, wsc[64 + k], wsc[96 + k]) + S, 0.f);
        }
        float acc[32];
#pragma unroll
        for (int m = 0; m < 32; ++m) acc[m] = b_u2[m];
#pragma unroll
        for (int k = 0; k < 32; ++k)
#pragma unroll
            for (int m = 0; m < 32; ++m)
                acc[m] = fmaf(z[k], w_u2[k * 32 + m], acc[m]);
        // own row: reads above complete before overwrite, no cross-thread use
#pragma unroll
        for (int k = 0; k < 32; ++k) sld[tid * 33 + k] = acc[k];
    }
    __syncthreads();

    int total = n * 32;
    for (int f = tid; f < total; f += 256) {
        int i = f >> 5, k = f & 31;
        __builtin_nontemporal_store(sld[i * 33 + k], &out[(size_t)e0 * 32 + f]);
    }
}

extern "C" void kernel_launch(void* const* d_in, const int* in_sizes, int n_in,
                              void* d_out, int out_size, void* d_ws, size_t ws_size,
                              hipStream_t stream) {
    const float* attr   = (const float*)d_in[0];
    const int*   eidx   = (const int*)d_in[1];   // src = first E entries
    const float* w_v2h  = (const float*)d_in[3];
    const float* b_v2h  = (const float*)d_in[4];
    const float* w_t1   = (const float*)d_in[5];
    const float* b_t1   = (const float*)d_in[6];
    const float* w_t2   = (const float*)d_in[7];
    const float* b_t2   = (const float*)d_in[8];
    const float* w_u1   = (const float*)d_in[9];
    const float* b_u1   = (const float*)d_in[10];
    const float* w_u2   = (const float*)d_in[11];
    const float* b_u2   = (const float*)d_in[12];
    float* out = (float*)d_out;

    int E = in_sizes[0];          // edge_attr is E x 1
    int C = in_sizes[2];          // candidate_idxs length

    // ws layout: buf (C*68 f32) | sarr (C*32 f32) | wsc (1280 f32) | pk (E f32x2)
    float*  buf  = (float*)d_ws;
    float*  sarr = buf + (size_t)C * 68;
    float*  wsc  = sarr + (size_t)C * 32;
    float2* pk   = (float2*)(wsc + 1280);
    size_t need_base = ((size_t)C * 100 + 1280) * 4;
    int useKey = (C <= 16384 && ws_size >= need_base + (size_t)E * 8) ? 1 : 0;

    hipMemsetAsync(buf, 0, (size_t)C * 68 * sizeof(float), stream);

    precompute_kernel<<<1, 1024, 0, stream>>>(w_v2h, b_v2h, w_t1, b_t1,
                                              w_t2, b_t2, w_u1, b_u1, wsc);

    if (useKey)
        pass0_kernel<<<(E + 255) / 256, 256, 0, stream>>>(attr, eidx, wsc, pk, E);

    phase1_kernel<<<NP1 * CH1, 1024, 0, stream>>>(pk, attr, eidx, wsc, buf,
                                                  E, C, useKey);

    sscore_kernel<<<((unsigned)C * 32u + 255) / 256, 256, 0, stream>>>(buf, wsc,
                                                                       sarr, C);

    phase2_kernel<<<(E + 255) / 256, 256, 0, stream>>>(attr, eidx, sarr, wsc,
                                                       w_u2, b_u2, out, E);
}